// Round 4
// baseline (191.158 us; speedup 1.0000x reference)
//
#include <hip/hip_runtime.h>
#include <hip/hip_bf16.h>

#define NROWS  8192
#define DIM    256
#define NCLASS 512
#define MARGIN 0.3f

using bf16x8 = __attribute__((ext_vector_type(8))) short;
using f32x4  = __attribute__((ext_vector_type(4))) float;

__device__ inline ushort f2bf(float f) {
    __hip_bfloat16 h = __float2bfloat16(f);
    return *reinterpret_cast<ushort*>(&h);
}
__device__ inline float bf2f(ushort u) {
    return __uint_as_float(((unsigned)u) << 16);
}
// Order-preserving float<->uint transform: bitwise atomicMax/Min == float max/min.
__device__ inline unsigned f2ord(float f) {
    unsigned b = __float_as_uint(f);
    return (b & 0x80000000u) ? ~b : (b | 0x80000000u);
}
__device__ inline float ord2f(unsigned u) {
    return __uint_as_float((u & 0x80000000u) ? (u & 0x7FFFFFFFu) : ~u);
}
// Async global->LDS, 16B per lane. LDS dest is wave-uniform base + lane*16.
__device__ inline void ld16_g2l(const void* g, void* l) {
    __builtin_amdgcn_global_load_lds(
        (const __attribute__((address_space(1))) unsigned int*)g,
        (__attribute__((address_space(3))) unsigned int*)l, 16, 0, 0);
}

// ---- workspace layout (bytes) ----
#define XBS_OFF 0u            // 8192*256*2 = 4194304  sorted bf16 rows
#define SQS_OFF 4194304u      // 32768  sorted ||x||^2
#define TGT_OFF 4227072u      // 32768  sorted targets (int)
#define PMX_OFF 4259840u      // 32768  ordered-uint max over positives of (sqc-2acc)
#define NMN_OFF 4292608u      // 32768  ordered-uint min over negatives
#define BIN_OFF 4325376u      // 2048   class bin cursors
#define TIK_OFF 4327424u      // 4      completion ticket

// K1: one block. Histogram of targets -> exclusive scan -> bin cursors.
// Also zeroes the gram completion ticket.
__global__ __launch_bounds__(512) void hist_scan_kernel(
    const int* __restrict__ tgt, int* __restrict__ bincur,
    unsigned* __restrict__ ticket)
{
    __shared__ int h[NCLASS];
    int tid = threadIdx.x;
    h[tid] = 0;
    if (tid == 0) *ticket = 0u;
    __syncthreads();
    for (int k = 0; k < NROWS / NCLASS; ++k)
        atomicAdd(&h[tgt[tid + k * NCLASS]], 1);
    __syncthreads();
    int cnt = h[tid];
    for (int ofs = 1; ofs < NCLASS; ofs <<= 1) {
        int v = (tid >= ofs) ? h[tid - ofs] : 0;
        __syncthreads();
        h[tid] += v;
        __syncthreads();
    }
    bincur[tid] = h[tid] - cnt;
}

// K2: one wave per row. Normalize fp32 -> bf16, scatter to class-sorted slot.
__global__ __launch_bounds__(256) void norm_scatter_kernel(
    const float* __restrict__ in, const int* __restrict__ tgt,
    int* __restrict__ bincur, ushort* __restrict__ xbs,
    float* __restrict__ sqs, int* __restrict__ tgts,
    unsigned* __restrict__ pmax, unsigned* __restrict__ nmin)
{
    int row  = blockIdx.x * 4 + (threadIdx.x >> 6);
    int lane = threadIdx.x & 63;
    float4 v = ((const float4*)(in + (size_t)row * DIM))[lane];
    float ss = v.x * v.x + v.y * v.y + v.z * v.z + v.w * v.w;
#pragma unroll
    for (int m = 1; m < 64; m <<= 1) ss += __shfl_xor(ss, m, 64);
    float inv = 1.0f / (sqrtf(ss) + 1e-12f);

    ushort4 st;
    st.x = f2bf(v.x * inv); st.y = f2bf(v.y * inv);
    st.z = f2bf(v.z * inv); st.w = f2bf(v.w * inv);

    int t = 0, dst = 0;
    if (lane == 0) { t = tgt[row]; dst = atomicAdd(&bincur[t], 1); }
    dst = __shfl(dst, 0); t = __shfl(t, 0);

    ((ushort4*)(xbs + (size_t)dst * DIM))[lane] = st;

    float a0 = bf2f(st.x), a1 = bf2f(st.y), a2 = bf2f(st.z), a3 = bf2f(st.w);
    float s2 = a0 * a0 + a1 * a1 + a2 * a2 + a3 * a3;
#pragma unroll
    for (int m = 1; m < 64; m <<= 1) s2 += __shfl_xor(s2, m, 64);
    if (lane == 0) {
        sqs[dst]  = s2;
        tgts[dst] = t;
        pmax[dst] = 0x007FFFFFu;  // f2ord(-inf)
        nmin[dst] = 0xFF800000u;  // f2ord(+inf)
    }
}

// K3: fused gram + hard-pos/hard-neg + finalize. Round-0 structure (shared
// double-buffered LDS staging, proven XOR-swizzle pair, per-stage barrier)
// with the occupancy fix: 32 rows/wave (afrag[2][8] = 64 AGPRs instead of
// 128) drops total regs ~256 -> ~150/lane, i.e. 2 -> 3 waves/SIMD, and
// grid 1024 (128 rows x 512 cols per block) puts 3 independent lockstep
// blocks on each CU. Rounds 2/3 proved latency dies at 2 waves/SIMD; round-0
// counters (29%+27%+29% = serial sum) showed 2 lockstep blocks can't overlap
// pipes. 3 independent streams/CU interleave their MFMA/LDS/VALU phases.
// Last block (ticket) computes the final loss (replaces the old K4 kernel).
__global__ __launch_bounds__(256, 3) void gram_kernel(
    const ushort* __restrict__ xbs, const float* __restrict__ sqs,
    const int* __restrict__ tgts, unsigned* __restrict__ pmax,
    unsigned* __restrict__ nmin, unsigned* __restrict__ ticket,
    float* __restrict__ out)
{
    __shared__ struct {
        char  buf[2][16384];   // B stage buffers: 32 cols x 512B, swizzled
        float sqc[512];        // per-col ||x||^2 for this 512-col chunk
        int   tgc[512];        // per-col class
        int   tga[128];        // per-row class for this block's 128 rows
    } sm;
    __shared__ unsigned lastblk;

    const int wave = threadIdx.x >> 6;
    const int lane = threadIdx.x & 63;
    const int l15  = lane & 15;
    const int quad = lane >> 4;

    // XCD supertile swizzle (bijective): grid 1024 = 8 XCD x 128 blocks.
    // Per XCD: 16 bx x 8 by -> rows 16*128=2048 (1MB) + cols 8*512=4096 (2MB)
    // = 3MB < 4MB per-XCD L2.
    const int id  = blockIdx.x;
    const int xcd = id & 7;
    const int w   = id >> 3;                    // 0..127
    const int bx  = (xcd & 3) * 16 + (w & 15);  // 0..63  (128 rows each)
    const int by  = (xcd >> 2) * 8 + (w >> 4);  // 0..15  (512 cols each)

    const int wbase = bx * 128 + wave * 32;     // this wave's first row
    const int nbase = by * 512;

    // Stage per-chunk metadata into LDS (covered by the prologue barrier).
    {
        int c = threadIdx.x * 2;
        sm.sqc[c]     = sqs[nbase + c];
        sm.sqc[c + 1] = sqs[nbase + c + 1];
        sm.tgc[c]     = tgts[nbase + c];
        sm.tgc[c + 1] = tgts[nbase + c + 1];
        if (threadIdx.x < 128)
            sm.tga[threadIdx.x] = tgts[bx * 128 + threadIdx.x];
    }

    // Preload A fragments: 2 tiles x full K=256 (64 regs, AGPR-backed).
    bf16x8 afrag[2][8];
#pragma unroll
    for (int a = 0; a < 2; ++a) {
        const ushort* arow = xbs + (size_t)(wbase + a * 16 + l15) * DIM + quad * 8;
#pragma unroll
        for (int kk = 0; kk < 8; ++kk)
            afrag[a][kk] = *(const bf16x8*)(arow + kk * 32);
    }
    const int rlo = tgts[wbase];        // sorted => wave row-class range
    const int rhi = tgts[wbase + 31];
    // Hoist this lane's 8 row-classes (kills per-stage LDS scalar reads in
    // the slow path).
    int tgr[8];
#pragma unroll
    for (int a = 0; a < 2; ++a)
#pragma unroll
        for (int i = 0; i < 4; ++i)
            tgr[a * 4 + i] = tgts[wbase + a * 16 + quad * 4 + i];

    // Per-lane global source offsets for staging (xor-swizzle compensation).
    // Stage instr i writes LDS [i*1024,(i+1)*1024): col=2i+(lane>>5),
    // slot=lane&31, which must hold logical chunk c = slot ^ (col&7).
    const int colh = lane >> 5, c31 = lane & 31;
    int offs[4];
#pragma unroll
    for (int j = 0; j < 4; ++j)
        offs[j] = colh * 512 + ((c31 ^ ((2 * j + colh) & 7)) << 4);

    const char* xbs_b = (const char*)xbs;

    // Prologue: issue stage 0 (16 KB = 16 DMA instrs, 4 per wave).
    {
        const char* gbase = xbs_b + (size_t)nbase * 512;
#pragma unroll
        for (int j = 0; j < 4; ++j) {
            int i = wave * 4 + j;
            ld16_g2l(gbase + i * 1024 + offs[j], sm.buf[0] + i * 1024);
        }
    }
    __syncthreads();  // drains prologue DMA + metadata writes

    float pm[8], nm[8];
#pragma unroll
    for (int j = 0; j < 8; ++j) { pm[j] = -__builtin_inff(); nm[j] = __builtin_inff(); }

#pragma unroll 1
    for (int s = 0; s < 16; ++s) {
        // Issue stage s+1 into the other buffer (lands during this stage's
        // compute; the stage-end barrier drain is then ~free).
        if (s < 15) {
            const char* gbase = xbs_b + (size_t)(nbase + (s + 1) * 32) * 512;
            char* lbase = sm.buf[(s + 1) & 1];
#pragma unroll
            for (int j = 0; j < 4; ++j) {
                int i = wave * 4 + j;
                ld16_g2l(gbase + i * 1024 + offs[j], lbase + i * 1024);
            }
        }
        // Compute the two 16-col tiles of the current buffer.
        const char* bufc = sm.buf[s & 1];
#pragma unroll
        for (int u = 0; u < 2; ++u) {
            const int t16 = s * 32 + u * 16;
            bf16x8 bfrag[8];
#pragma unroll
            for (int kk = 0; kk < 8; ++kk)
                bfrag[kk] = *(const bf16x8*)(bufc + u * 8192 + l15 * 512 +
                                             (((quad + 4 * kk) ^ (l15 & 7)) << 4));
            f32x4 acc4[2];
#pragma unroll
            for (int a = 0; a < 2; ++a) {
                f32x4 acc = {0.f, 0.f, 0.f, 0.f};
#pragma unroll
                for (int kk = 0; kk < 8; ++kk)
                    acc = __builtin_amdgcn_mfma_f32_16x16x32_bf16(afrag[a][kk], bfrag[kk], acc, 0, 0, 0);
                acc4[a] = acc;
            }
            const float sqc = sm.sqc[t16 + l15];
            const int clo = sm.tgc[t16], chi = sm.tgc[t16 + 15];
            if (rlo <= chi && clo <= rhi) {
                // slow path: tile may contain positives
                const int tc = sm.tgc[t16 + l15];
#pragma unroll
                for (int a = 0; a < 2; ++a)
#pragma unroll
                    for (int i = 0; i < 4; ++i) {
                        const float v = fmaf(acc4[a][i], -2.0f, sqc);
                        const bool same = (tgr[a * 4 + i] == tc);
                        pm[a * 4 + i] = fmaxf(pm[a * 4 + i], same ? v : -__builtin_inff());
                        nm[a * 4 + i] = fminf(nm[a * 4 + i], same ? __builtin_inff() : v);
                    }
            } else {
                // fast path: negatives only
#pragma unroll
                for (int a = 0; a < 2; ++a)
#pragma unroll
                    for (int i = 0; i < 4; ++i)
                        nm[a * 4 + i] = fminf(nm[a * 4 + i], fmaf(acc4[a][i], -2.0f, sqc));
            }
        }
        __syncthreads();  // stage-s+1 DMA landed during compute -> cheap drain
    }

    // Reduce across the 16 column-lanes (same quad), then one atomic per row.
#pragma unroll
    for (int m = 1; m < 16; m <<= 1) {
#pragma unroll
        for (int j = 0; j < 8; ++j) {
            pm[j] = fmaxf(pm[j], __shfl_xor(pm[j], m, 64));
            nm[j] = fminf(nm[j], __shfl_xor(nm[j], m, 64));
        }
    }
    if (l15 == 0) {
#pragma unroll
        for (int a = 0; a < 2; ++a)
#pragma unroll
            for (int i = 0; i < 4; ++i) {
                int r = wbase + a * 16 + quad * 4 + i;
                atomicMax(&pmax[r], f2ord(pm[a * 4 + i]));
                atomicMin(&nmin[r], f2ord(nm[a * 4 + i]));
            }
    }

    // ---- fused finalize: last block to finish computes the loss ----
    __threadfence();
    if (threadIdx.x == 0)
        lastblk = (atomicAdd(ticket, 1u) == 1023u) ? 1u : 0u;
    __syncthreads();
    if (lastblk) {
        __threadfence();  // acquire: all blocks' pmax/nmin RMWs precede ticket==1023
        double s = 0.0;
        for (int r = threadIdx.x; r < NROWS; r += 256) {
            unsigned pu = __hip_atomic_load(&pmax[r], __ATOMIC_RELAXED,
                                            __HIP_MEMORY_SCOPE_AGENT);
            unsigned nu = __hip_atomic_load(&nmin[r], __ATOMIC_RELAXED,
                                            __HIP_MEMORY_SCOPE_AGENT);
            float pe = ord2f(pu);
            float ne = ord2f(nu);
            float ap = sqrtf(fmaxf(sqs[r] + pe, 0.0f));
            float an = (ne > 1e30f) ? (MARGIN + 1.0f) : sqrtf(fmaxf(sqs[r] + ne, 0.0f));
            s += (double)fmaxf(ap - an + MARGIN, 0.0f);
        }
#pragma unroll
        for (int m = 1; m < 64; m <<= 1) s += __shfl_xor(s, m, 64);
        __shared__ double sh[4];
        if ((threadIdx.x & 63) == 0) sh[threadIdx.x >> 6] = s;
        __syncthreads();
        if (threadIdx.x == 0)
            out[0] = (float)((sh[0] + sh[1] + sh[2] + sh[3]) / (double)NROWS);
    }
}

extern "C" void kernel_launch(void* const* d_in, const int* in_sizes, int n_in,
                              void* d_out, int out_size, void* d_ws, size_t ws_size,
                              hipStream_t stream) {
    const float* in  = (const float*)d_in[0];
    const int*   tgt = (const int*)d_in[1];
    float*       out = (float*)d_out;

    char* ws = (char*)d_ws;
    ushort*   xbs    = (ushort*)(ws + XBS_OFF);
    float*    sqs    = (float*)(ws + SQS_OFF);
    int*      tgts   = (int*)(ws + TGT_OFF);
    unsigned* pmax   = (unsigned*)(ws + PMX_OFF);
    unsigned* nmin   = (unsigned*)(ws + NMN_OFF);
    int*      bincur = (int*)(ws + BIN_OFF);
    unsigned* ticket = (unsigned*)(ws + TIK_OFF);

    hist_scan_kernel<<<1, 512, 0, stream>>>(tgt, bincur, ticket);
    norm_scatter_kernel<<<NROWS / 4, 256, 0, stream>>>(in, tgt, bincur, xbs, sqs, tgts, pmax, nmin);
    gram_kernel<<<1024, 256, 0, stream>>>(xbs, sqs, tgts, pmax, nmin, ticket, out);
}